// Round 4
// baseline (316.275 us; speedup 1.0000x reference)
//
#include <hip/hip_runtime.h>
#include <math.h>

#define BB 256
#define VV 50257
#define L2E 1.4426950408889634f

// ---------------- Kernel 1: partial softmax stats per (row, quarter) ----------------
#define QS 12576   // quarter size (multiple of 32)

__global__ __launch_bounds__(512) void partial_stats_kernel(
    const float* __restrict__ w, float2* __restrict__ partial, int V)
{
    const int bid = blockIdx.x;          // 0..1023
    const int row = bid >> 2, q = bid & 3;
    const int lo = q * QS, hi = min(V, lo + QS);
    const int n = hi - lo;
    const float* p = w + (size_t)row * V + lo;
    const int tid = threadIdx.x; const int nt = 512;

    const int a = (int)(((16u - ((uintptr_t)p & 15u)) & 15u) >> 2);
    const int nv4 = (n - a) >> 2;
    const float4* pv = (const float4*)(p + a);
    const int tail0 = a + (nv4 << 2);

    // pass 1: max
    float m0 = -INFINITY, m1 = -INFINITY, m2 = -INFINITY, m3 = -INFINITY;
    for (int i = tid; i < a; i += nt) m0 = fmaxf(m0, p[i]);
    for (int i = tail0 + tid; i < n; i += nt) m0 = fmaxf(m0, p[i]);
    {
        int i = tid;
        for (; i + 3 * nt < nv4; i += 4 * nt) {
            float4 v0 = pv[i], v1 = pv[i + nt], v2 = pv[i + 2 * nt], v3 = pv[i + 3 * nt];
            m0 = fmaxf(m0, fmaxf(fmaxf(v0.x, v0.y), fmaxf(v0.z, v0.w)));
            m1 = fmaxf(m1, fmaxf(fmaxf(v1.x, v1.y), fmaxf(v1.z, v1.w)));
            m2 = fmaxf(m2, fmaxf(fmaxf(v2.x, v2.y), fmaxf(v2.z, v2.w)));
            m3 = fmaxf(m3, fmaxf(fmaxf(v3.x, v3.y), fmaxf(v3.z, v3.w)));
        }
        for (; i < nv4; i += nt) {
            float4 v0 = pv[i];
            m0 = fmaxf(m0, fmaxf(fmaxf(v0.x, v0.y), fmaxf(v0.z, v0.w)));
        }
    }
    float m = fmaxf(fmaxf(m0, m1), fmaxf(m2, m3));
    #pragma unroll
    for (int off = 32; off >= 1; off >>= 1) m = fmaxf(m, __shfl_xor(m, off, 64));
    __shared__ float sred[8], ssum[8];
    const int wave = tid >> 6, lane = tid & 63;
    if (lane == 0) sred[wave] = m;
    __syncthreads();
    float M = sred[0];
    #pragma unroll
    for (int i = 1; i < 8; ++i) M = fmaxf(M, sred[i]);
    const float mML2 = -M * L2E;

    // pass 2: sum of exp2((x-M)*L2E) == sum e^(x-M); quarter is L2-resident now
    float s0 = 0.f, s1 = 0.f, s2 = 0.f, s3 = 0.f;
    for (int i = tid; i < a; i += nt) s0 += exp2f(fmaf(p[i], L2E, mML2));
    for (int i = tail0 + tid; i < n; i += nt) s0 += exp2f(fmaf(p[i], L2E, mML2));
    {
        int i = tid;
        for (; i + 3 * nt < nv4; i += 4 * nt) {
            float4 v0 = pv[i], v1 = pv[i + nt], v2 = pv[i + 2 * nt], v3 = pv[i + 3 * nt];
            s0 += exp2f(fmaf(v0.x, L2E, mML2)) + exp2f(fmaf(v0.y, L2E, mML2))
                + exp2f(fmaf(v0.z, L2E, mML2)) + exp2f(fmaf(v0.w, L2E, mML2));
            s1 += exp2f(fmaf(v1.x, L2E, mML2)) + exp2f(fmaf(v1.y, L2E, mML2))
                + exp2f(fmaf(v1.z, L2E, mML2)) + exp2f(fmaf(v1.w, L2E, mML2));
            s2 += exp2f(fmaf(v2.x, L2E, mML2)) + exp2f(fmaf(v2.y, L2E, mML2))
                + exp2f(fmaf(v2.z, L2E, mML2)) + exp2f(fmaf(v2.w, L2E, mML2));
            s3 += exp2f(fmaf(v3.x, L2E, mML2)) + exp2f(fmaf(v3.y, L2E, mML2))
                + exp2f(fmaf(v3.z, L2E, mML2)) + exp2f(fmaf(v3.w, L2E, mML2));
        }
        for (; i < nv4; i += nt) {
            float4 v0 = pv[i];
            s0 += exp2f(fmaf(v0.x, L2E, mML2)) + exp2f(fmaf(v0.y, L2E, mML2))
                + exp2f(fmaf(v0.z, L2E, mML2)) + exp2f(fmaf(v0.w, L2E, mML2));
        }
    }
    float s = (s0 + s1) + (s2 + s3);
    #pragma unroll
    for (int off = 32; off >= 1; off >>= 1) s += __shfl_xor(s, off, 64);
    if (lane == 0) ssum[wave] = s;
    __syncthreads();
    if (tid == 0) {
        float S = 0.f;
        #pragma unroll
        for (int i = 0; i < 8; ++i) S += ssum[i];
        partial[bid] = make_float2(M, S);
    }
}

// ---------------- Kernel 2: combine partials -> per-row C = M*log2e + log2(S) ----------------
__global__ void combine_kernel(const float2* __restrict__ partial, float* __restrict__ Cc)
{
    const int b = threadIdx.x;   // 256 threads, 1 block
    float2 p0 = partial[b * 4 + 0], p1 = partial[b * 4 + 1];
    float2 p2 = partial[b * 4 + 2], p3 = partial[b * 4 + 3];
    float M = fmaxf(fmaxf(p0.x, p1.x), fmaxf(p2.x, p3.x));
    float S = p0.y * exp2f((p0.x - M) * L2E) + p1.y * exp2f((p1.x - M) * L2E)
            + p2.y * exp2f((p2.x - M) * L2E) + p3.y * exp2f((p3.x - M) * L2E);
    Cc[b] = M * L2E + log2f(S);
}

// ---------------- Kernel 3: branchless LDS scatter-accumulate, half-range per block ----------------
#define RS 25152   // half-range (multiple of 32); LDS acc = RS+64 floats = 100.9 KB

__global__ __launch_bounds__(1024, 4) void scatter_kernel(
    const float* __restrict__ w, const int* __restrict__ idx,
    const float* __restrict__ Cc, float* __restrict__ avg, int V)
{
    __shared__ float acc[RS + 64];

    // siblings (q=0,1) of a row on the same XCD, adjacent slots -> concurrent
    const int bid = blockIdx.x;          // 0..511
    const int xcd = bid & 7;
    const int s   = bid >> 3;            // 0..63
    const int row = xcd + 8 * (s >> 1);
    const int q   = s & 1;
    const int lo  = q * RS;
    const int hi  = min(V, lo + RS);
    const unsigned range = (unsigned)(hi - lo);
    const int tid = threadIdx.x; const int nt = 1024;

    for (int i = tid; i < RS; i += nt) acc[i] = 0.f;
    const float mC = -Cc[row];
    const unsigned dummy = (unsigned)(RS + (tid & 63));
    __syncthreads();

    const size_t base = (size_t)row * V;
    const float* wr = w + base;
    const int*   ir = idx + base;
    const int a = (int)(((16u - ((uintptr_t)wr & 15u)) & 15u) >> 2);
    const int nv4 = (V - a) >> 2;
    const int tail0 = a + (nv4 << 2);
    const float4* wv4 = (const float4*)(wr + a);
    const int4*   iv4 = (const int4*)(ir + a);

#define PROC1(idv, xv)                                                          \
    do {                                                                        \
        unsigned off = (unsigned)(idv) - (unsigned)lo;                          \
        unsigned slot = (off < range) ? off : dummy;  /* cndmask, no branch */  \
        atomicAdd(&acc[slot], exp2f(fmaf((xv), L2E, mC)));                      \
    } while (0)
#define PROC4(iv, xv)                                                           \
    do {                                                                        \
        PROC1((iv).x, (xv).x); PROC1((iv).y, (xv).y);                           \
        PROC1((iv).z, (xv).z); PROC1((iv).w, (xv).w);                           \
    } while (0)

    for (int i = tid; i < a; i += nt) PROC1(ir[i], wr[i]);
    for (int i = tail0 + tid; i < V; i += nt) PROC1(ir[i], wr[i]);

    int i = tid;
    // 8-deep: 16 vector loads (256B) in flight per wave
    for (; i + 7 * nt < nv4; i += 8 * nt) {
        int4   i0 = iv4[i],          i1 = iv4[i + nt],     i2 = iv4[i + 2 * nt], i3 = iv4[i + 3 * nt];
        int4   i4 = iv4[i + 4 * nt], i5 = iv4[i + 5 * nt], i6 = iv4[i + 6 * nt], i7 = iv4[i + 7 * nt];
        float4 x0 = wv4[i],          x1 = wv4[i + nt],     x2 = wv4[i + 2 * nt], x3 = wv4[i + 3 * nt];
        float4 x4 = wv4[i + 4 * nt], x5 = wv4[i + 5 * nt], x6 = wv4[i + 6 * nt], x7 = wv4[i + 7 * nt];
        PROC4(i0, x0); PROC4(i1, x1); PROC4(i2, x2); PROC4(i3, x3);
        PROC4(i4, x4); PROC4(i5, x5); PROC4(i6, x6); PROC4(i7, x7);
    }
    for (; i + 3 * nt < nv4; i += 4 * nt) {
        int4   i0 = iv4[i], i1 = iv4[i + nt], i2 = iv4[i + 2 * nt], i3 = iv4[i + 3 * nt];
        float4 x0 = wv4[i], x1 = wv4[i + nt], x2 = wv4[i + 2 * nt], x3 = wv4[i + 3 * nt];
        PROC4(i0, x0); PROC4(i1, x1); PROC4(i2, x2); PROC4(i3, x3);
    }
    for (; i < nv4; i += nt) {
        int4 i0 = iv4[i]; float4 x0 = wv4[i];
        PROC4(i0, x0);
    }
    __syncthreads();

    for (int j = tid; j < (int)range; j += nt)
        __builtin_nontemporal_store(acc[j], &avg[base + lo + j]);
#undef PROC1
#undef PROC4
}

// ---------------- Kernel 4: weights^T via LDS transpose tile ----------------
#define T3V 64
#define T3B 64

__global__ __launch_bounds__(256) void transpose_kernel(
    const float* __restrict__ w, const float* __restrict__ Cc,
    float* __restrict__ wT, int Bn, int V)
{
    __shared__ float tile[T3V][T3B + 1];
    __shared__ float sC[T3B];

    const int v0 = blockIdx.x * T3V;
    const int b0 = blockIdx.y * T3B;
    const int tid = threadIdx.x;

    if (tid < T3B) sC[tid] = -Cc[b0 + tid];
    __syncthreads();

    const int tx = tid & 63;   // v offset
    const int ty = tid >> 6;   // 0..3
    const int v  = v0 + tx;
    const bool vok = (v < V);

    #pragma unroll
    for (int it = 0; it < T3B / 4; ++it) {
        const int bl = ty + 4 * it;
        float wgt = 0.f;
        if (vok) {
            const float x = w[(size_t)(b0 + bl) * V + v];
            wgt = exp2f(fmaf(x, L2E, sC[bl]));
        }
        tile[tx][bl] = wgt;
    }
    __syncthreads();

    const int bx = tid & 63;   // b offset -> 256B coalesced stores
    const int vy = tid >> 6;
    #pragma unroll
    for (int it = 0; it < T3V / 4; ++it) {
        const int vr = vy + 4 * it;
        const int v2 = v0 + vr;
        if (v2 < V) __builtin_nontemporal_store(tile[vr][bx], &wT[(size_t)v2 * Bn + b0 + bx]);
    }
}

extern "C" void kernel_launch(void* const* d_in, const int* in_sizes, int n_in,
                              void* d_out, int out_size, void* d_ws, size_t ws_size,
                              hipStream_t stream) {
    const int*   indices = (const int*)d_in[0];
    const float* w_es    = (const float*)d_in[1];
    float* avg = (float*)d_out;
    float* wT  = (float*)d_out + (size_t)BB * VV;
    float2* partial = (float2*)d_ws;                       // 1024 float2
    float*  Cc      = (float*)((char*)d_ws + 1024 * sizeof(float2));  // 256 floats

    partial_stats_kernel<<<BB * 4, 512, 0, stream>>>(w_es, partial, VV);
    combine_kernel<<<1, BB, 0, stream>>>(partial, Cc);
    scatter_kernel<<<BB * 2, 1024, 0, stream>>>(w_es, indices, Cc, avg, VV);

    dim3 g4((VV + T3V - 1) / T3V, BB / T3B);
    transpose_kernel<<<g4, 256, 0, stream>>>(w_es, Cc, wT, BB, VV);
}

// Round 5
// 264.316 us; speedup vs baseline: 1.1966x; 1.1966x over previous
//
#include <hip/hip_runtime.h>
#include <math.h>

#define BB 256
#define VV 50257
#define L2E 1.4426950408889634f

// ---------------- Kernel 1: partial softmax stats per (row, quarter) ----------------
#define QS 12576   // quarter size (multiple of 32)

__global__ __launch_bounds__(512) void partial_stats_kernel(
    const float* __restrict__ w, float2* __restrict__ partial, int V)
{
    const int bid = blockIdx.x;          // 0..1023
    const int row = bid >> 2, q = bid & 3;
    const int lo = q * QS, hi = min(V, lo + QS);
    const int n = hi - lo;
    const float* p = w + (size_t)row * V + lo;
    const int tid = threadIdx.x; const int nt = 512;

    const int a = (int)(((16u - ((uintptr_t)p & 15u)) & 15u) >> 2);
    const int nv4 = (n - a) >> 2;
    const float4* pv = (const float4*)(p + a);
    const int tail0 = a + (nv4 << 2);

    // pass 1: max
    float m0 = -INFINITY, m1 = -INFINITY, m2 = -INFINITY, m3 = -INFINITY;
    for (int i = tid; i < a; i += nt) m0 = fmaxf(m0, p[i]);
    for (int i = tail0 + tid; i < n; i += nt) m0 = fmaxf(m0, p[i]);
    {
        int i = tid;
        for (; i + 3 * nt < nv4; i += 4 * nt) {
            float4 v0 = pv[i], v1 = pv[i + nt], v2 = pv[i + 2 * nt], v3 = pv[i + 3 * nt];
            m0 = fmaxf(m0, fmaxf(fmaxf(v0.x, v0.y), fmaxf(v0.z, v0.w)));
            m1 = fmaxf(m1, fmaxf(fmaxf(v1.x, v1.y), fmaxf(v1.z, v1.w)));
            m2 = fmaxf(m2, fmaxf(fmaxf(v2.x, v2.y), fmaxf(v2.z, v2.w)));
            m3 = fmaxf(m3, fmaxf(fmaxf(v3.x, v3.y), fmaxf(v3.z, v3.w)));
        }
        for (; i < nv4; i += nt) {
            float4 v0 = pv[i];
            m0 = fmaxf(m0, fmaxf(fmaxf(v0.x, v0.y), fmaxf(v0.z, v0.w)));
        }
    }
    float m = fmaxf(fmaxf(m0, m1), fmaxf(m2, m3));
    #pragma unroll
    for (int off = 32; off >= 1; off >>= 1) m = fmaxf(m, __shfl_xor(m, off, 64));
    __shared__ float sred[8], ssum[8];
    const int wave = tid >> 6, lane = tid & 63;
    if (lane == 0) sred[wave] = m;
    __syncthreads();
    float M = sred[0];
    #pragma unroll
    for (int i = 1; i < 8; ++i) M = fmaxf(M, sred[i]);
    const float mML2 = -M * L2E;

    // pass 2: sum of exp
    float s0 = 0.f, s1 = 0.f, s2 = 0.f, s3 = 0.f;
    for (int i = tid; i < a; i += nt) s0 += exp2f(fmaf(p[i], L2E, mML2));
    for (int i = tail0 + tid; i < n; i += nt) s0 += exp2f(fmaf(p[i], L2E, mML2));
    {
        int i = tid;
        for (; i + 3 * nt < nv4; i += 4 * nt) {
            float4 v0 = pv[i], v1 = pv[i + nt], v2 = pv[i + 2 * nt], v3 = pv[i + 3 * nt];
            s0 += exp2f(fmaf(v0.x, L2E, mML2)) + exp2f(fmaf(v0.y, L2E, mML2))
                + exp2f(fmaf(v0.z, L2E, mML2)) + exp2f(fmaf(v0.w, L2E, mML2));
            s1 += exp2f(fmaf(v1.x, L2E, mML2)) + exp2f(fmaf(v1.y, L2E, mML2))
                + exp2f(fmaf(v1.z, L2E, mML2)) + exp2f(fmaf(v1.w, L2E, mML2));
            s2 += exp2f(fmaf(v2.x, L2E, mML2)) + exp2f(fmaf(v2.y, L2E, mML2))
                + exp2f(fmaf(v2.z, L2E, mML2)) + exp2f(fmaf(v2.w, L2E, mML2));
            s3 += exp2f(fmaf(v3.x, L2E, mML2)) + exp2f(fmaf(v3.y, L2E, mML2))
                + exp2f(fmaf(v3.z, L2E, mML2)) + exp2f(fmaf(v3.w, L2E, mML2));
        }
        for (; i < nv4; i += nt) {
            float4 v0 = pv[i];
            s0 += exp2f(fmaf(v0.x, L2E, mML2)) + exp2f(fmaf(v0.y, L2E, mML2))
                + exp2f(fmaf(v0.z, L2E, mML2)) + exp2f(fmaf(v0.w, L2E, mML2));
        }
    }
    float s = (s0 + s1) + (s2 + s3);
    #pragma unroll
    for (int off = 32; off >= 1; off >>= 1) s += __shfl_xor(s, off, 64);
    if (lane == 0) ssum[wave] = s;
    __syncthreads();
    if (tid == 0) {
        float S = 0.f;
        #pragma unroll
        for (int i = 0; i < 8; ++i) S += ssum[i];
        partial[bid] = make_float2(M, S);
    }
}

// ---------------- Kernel 2: combine partials -> per-row C = M*log2e + log2(S) ----------------
__global__ void combine_kernel(const float2* __restrict__ partial, float* __restrict__ Cc)
{
    const int b = threadIdx.x;   // 256 threads, 1 block
    float2 p0 = partial[b * 4 + 0], p1 = partial[b * 4 + 1];
    float2 p2 = partial[b * 4 + 2], p3 = partial[b * 4 + 3];
    float M = fmaxf(fmaxf(p0.x, p1.x), fmaxf(p2.x, p3.x));
    float S = p0.y * exp2f((p0.x - M) * L2E) + p1.y * exp2f((p1.x - M) * L2E)
            + p2.y * exp2f((p2.x - M) * L2E) + p3.y * exp2f((p3.x - M) * L2E);
    Cc[b] = M * L2E + log2f(S);
}

// ---------------- Kernel 3: wave-private streaming LDS scatter, half-range per block ----------------
#define RS 25152   // half-range (multiple of 32); acc = 100,608 B
#define DEPTH 3
#define NW 8       // waves per block (512 threads)

typedef const __attribute__((address_space(1))) int glds_src_t;
typedef __attribute__((address_space(3))) int       glds_dst_t;

__global__ __launch_bounds__(512) void scatter_kernel(
    const float* __restrict__ w, const int* __restrict__ idx,
    const float* __restrict__ Cc, float* __restrict__ avg, int V)
{
    __shared__ float acc[RS];
    __shared__ __align__(16) int stag[NW * DEPTH * 512];  // [wave][slot][512]: idx 256 ints + w 256 floats

    // siblings (q=0,1) of a row on the same XCD, adjacent slots -> L2 share
    const int bid = blockIdx.x;          // 0..511
    const int xcd = bid & 7;
    const int s   = bid >> 3;            // 0..63
    const int row = xcd + 8 * (s >> 1);
    const int q   = s & 1;
    const int lo  = q * RS;
    const int hi  = min(V, lo + RS);
    const unsigned range = (unsigned)(hi - lo);
    const int tid  = threadIdx.x;
    const int wave = tid >> 6, lane = tid & 63;

    for (int i = tid; i < RS; i += 512) acc[i] = 0.f;
    const float mC = -Cc[row];

    const size_t base = (size_t)row * V;
    const float* wr = w + base;
    const int*   ir = idx + base;
    const int a = (int)(((16u - ((uintptr_t)wr & 15u)) & 15u) >> 2);  // same for ir (same elem offsets)
    const int nchunks = (V - a) >> 8;     // 256-element chunks, 16B-aligned
    const int tail0 = a + (nchunks << 8);

    __syncthreads();   // acc zeroed before any ds_add

#define PROC(idv, xv) do {                                                  \
        unsigned off = (unsigned)(idv) - (unsigned)lo;                      \
        if (off < range) atomicAdd(&acc[off], exp2f(fmaf((xv), L2E, mC))); \
    } while (0)

    // leftovers: [0,a) and [tail0, V)  (≤ ~260 elements total)
    for (int i = tid; i < a; i += 512) PROC(ir[i], wr[i]);
    for (int i = tail0 + tid; i < V; i += 512) PROC(ir[i], wr[i]);

    // wave-private streaming: wave handles chunks c = wave + NW*k
    const int n_w = (nchunks - wave + NW - 1) / NW;   // 24 or 25
    const int sb0 = wave * (DEPTH * 512);

    // prologue: issue DEPTH chunks (2 glds each: idx then w)
    #pragma unroll
    for (int d = 0; d < DEPTH; ++d) {
        if (d < n_w) {
            const int c = wave + NW * d;
            const int eoff = a + (c << 8) + (lane << 2);
            __builtin_amdgcn_global_load_lds((glds_src_t*)(ir + eoff),
                                             (glds_dst_t*)&stag[sb0 + d * 512], 16, 0, 0);
            __builtin_amdgcn_global_load_lds((glds_src_t*)(wr + eoff),
                                             (glds_dst_t*)&stag[sb0 + d * 512 + 256], 16, 0, 0);
        }
    }

    int slot = 0;
    for (int k = 0; k < n_w; ++k) {
        if (k <= n_w - 3)      { asm volatile("s_waitcnt vmcnt(4)" ::: "memory"); }
        else if (k == n_w - 2) { asm volatile("s_waitcnt vmcnt(2)" ::: "memory"); }
        else                   { asm volatile("s_waitcnt vmcnt(0)" ::: "memory"); }
        const int sb = sb0 + slot * 512;
        const int4   iv = *(const int4*)  &stag[sb + (lane << 2)];
        const float4 xv = *(const float4*)&stag[sb + 256 + (lane << 2)];
        PROC(iv.x, xv.x); PROC(iv.y, xv.y); PROC(iv.z, xv.z); PROC(iv.w, xv.w);
        // refill this slot with chunk k+DEPTH (ds_reads above already consumed: lgkm waits precede)
        if (k + DEPTH < n_w) {
            const int cn = wave + NW * (k + DEPTH);
            const int eoff = a + (cn << 8) + (lane << 2);
            __builtin_amdgcn_global_load_lds((glds_src_t*)(ir + eoff),
                                             (glds_dst_t*)&stag[sb], 16, 0, 0);
            __builtin_amdgcn_global_load_lds((glds_src_t*)(wr + eoff),
                                             (glds_dst_t*)&stag[sb + 256], 16, 0, 0);
        }
        slot = (slot == DEPTH - 1) ? 0 : slot + 1;
    }
    __syncthreads();

    for (int j = tid; j < (int)range; j += 512)
        __builtin_nontemporal_store(acc[j], &avg[base + lo + j]);
#undef PROC
}

// ---------------- Kernel 4: weights^T via LDS transpose tile ----------------
#define T3V 64
#define T3B 64

__global__ __launch_bounds__(256) void transpose_kernel(
    const float* __restrict__ w, const float* __restrict__ Cc,
    float* __restrict__ wT, int Bn, int V)
{
    __shared__ float tile[T3V][T3B + 1];
    __shared__ float sC[T3B];

    const int v0 = blockIdx.x * T3V;
    const int b0 = blockIdx.y * T3B;
    const int tid = threadIdx.x;

    if (tid < T3B) sC[tid] = -Cc[b0 + tid];
    __syncthreads();

    const int tx = tid & 63;   // v offset
    const int ty = tid >> 6;   // 0..3
    const int v  = v0 + tx;
    const bool vok = (v < V);

    #pragma unroll
    for (int it = 0; it < T3B / 4; ++it) {
        const int bl = ty + 4 * it;
        float wgt = 0.f;
        if (vok) {
            const float x = w[(size_t)(b0 + bl) * V + v];
            wgt = exp2f(fmaf(x, L2E, sC[bl]));
        }
        tile[tx][bl] = wgt;
    }
    __syncthreads();

    const int bx = tid & 63;   // b offset -> 256B coalesced stores
    const int vy = tid >> 6;
    #pragma unroll
    for (int it = 0; it < T3V / 4; ++it) {
        const int vr = vy + 4 * it;
        const int v2 = v0 + vr;
        if (v2 < V) __builtin_nontemporal_store(tile[vr][bx], &wT[(size_t)v2 * Bn + b0 + bx]);
    }
}

extern "C" void kernel_launch(void* const* d_in, const int* in_sizes, int n_in,
                              void* d_out, int out_size, void* d_ws, size_t ws_size,
                              hipStream_t stream) {
    const int*   indices = (const int*)d_in[0];
    const float* w_es    = (const float*)d_in[1];
    float* avg = (float*)d_out;
    float* wT  = (float*)d_out + (size_t)BB * VV;
    float2* partial = (float2*)d_ws;                                  // 1024 float2
    float*  Cc      = (float*)((char*)d_ws + 1024 * sizeof(float2));  // 256 floats

    partial_stats_kernel<<<BB * 4, 512, 0, stream>>>(w_es, partial, VV);
    combine_kernel<<<1, BB, 0, stream>>>(partial, Cc);
    scatter_kernel<<<BB * 2, 512, 0, stream>>>(w_es, indices, Cc, avg, VV);

    dim3 g4((VV + T3V - 1) / T3V, BB / T3B);
    transpose_kernel<<<g4, 256, 0, stream>>>(w_es, Cc, wT, BB, VV);
}